// Round 8
// baseline (545.114 us; speedup 1.0000x reference)
//
#include <hip/hip_runtime.h>

#define NN 50000
#define EE 800000
#define DD 128
#define DOUTC 64
#define SUBS 4
#define SUBCAP 32          // slots per sub-counter; per-sub degree ~Poisson(4), P(>32)~1e-22
#define BUCKET_BLKS 3125   // EE / 256
#define AGG_NB 6250        // NN / 8 nodes per pass-block
#define CNT4_BYTES (SUBS * NN * 4)   // 800 KB
#define CNT4_ZBLKS 196     // ceil(800000 / 4096)

typedef unsigned int uint;
typedef unsigned short ushort;
typedef __attribute__((ext_vector_type(8))) short bf16x8;
typedef __attribute__((ext_vector_type(4))) float f32x4;

__device__ __forceinline__ float bf2f(uint b) { return __uint_as_float(b << 16); }
__device__ __forceinline__ ushort f2bf(float f) {
    uint u = __float_as_uint(f);
    u += 0x7fffu + ((u >> 16) & 1u);   // round-to-nearest-even
    return (ushort)(u >> 16);
}

// ---------------- k_pre: zero cnt4 + transpose-convert weights to bf16 [n][k] ----------
struct PreArgs {
    const float *w1, *w2, *w3, *wfc;
    ushort *wt1, *wt2, *wt3, *wtfc;
    char* cnt4;
};

__global__ __launch_bounds__(256) void k_pre(PreArgs a) {
    int b = blockIdx.x, t = threadIdx.x;
    if (b < CNT4_ZBLKS) {
        size_t i = ((size_t)b * 256 + t) * 16;
        if (i < (size_t)CNT4_BYTES) *(uint4*)(a.cnt4 + i) = (uint4){0, 0, 0, 0};
    } else if (b < CNT4_ZBLKS + 192) {
        int b2 = b - CNT4_ZBLKS;
        const float* w = (b2 < 64) ? a.w1 : (b2 < 128) ? a.w2 : a.w3;
        ushort* wt = (b2 < 64) ? a.wt1 : (b2 < 128) ? a.wt2 : a.wt3;
        int idx = (b2 & 63) * 256 + t;         // idx = k*128 + n
        int k = idx >> 7, n = idx & 127;
        wt[n * DD + k] = f2bf(w[idx]);
    } else {
        int idx = (b - CNT4_ZBLKS - 192) * 256 + t;  // idx = k*64 + n
        int k = idx >> 6, n = idx & 63;
        a.wtfc[n * DD + k] = f2bf(a.wfc[idx]);
    }
}

// ---------------- k_bucket: edge scatter with 4-way striped counters ----------------
// colb row per node: 4 subs x 32 slots x 2B = 256B. cnt4 layout [sub][node] (striped).
__global__ __launch_bounds__(256) void k_bucket(
    const int* __restrict__ src, const int* __restrict__ dst,
    int* __restrict__ cnt4, ushort* __restrict__ colb) {
    int e = blockIdx.x * 256 + threadIdx.x;    // EE == BUCKET_BLKS*256 exactly
    int d = dst[e];
    int s = src[e];
    int sub = e & 3;
    int p = atomicAdd(&cnt4[sub * NN + d], 1);
    if (p < SUBCAP) colb[((size_t)d << 7) + sub * SUBCAP + p] = (ushort)s;
}

// ---------------- k_mm1: T = bf16( dinv * (x @ W1) ), x fp32, T feature-chunked ---------
// T layout: 4 chunks of [NN][32] bf16 (3.2 MB each). chunk = n>>5, offset = n&31.
// D lane layout (16x16x32): col = lane&15 = m, row = quad*4 + reg = n.
__global__ __launch_bounds__(256) void k_mm1(
    const float* __restrict__ X, const ushort* __restrict__ WT,
    const int* __restrict__ cnt4, ushort* __restrict__ T) {
    const int wave = threadIdx.x >> 6;
    const int lane = threadIdx.x & 63;
    const int m0w = blockIdx.x * 64 + wave * 16;
    if (m0w >= NN) return;                     // NN % 16 == 0
    const int m = m0w + (lane & 15);
    const int quad = lane >> 4;
    f32x4 acc[8];
#pragma unroll
    for (int nt = 0; nt < 8; ++nt) acc[nt] = (f32x4){0.f, 0.f, 0.f, 0.f};
    const float* Hrow = X + (size_t)m * DD;
#pragma unroll
    for (int kk = 0; kk < 4; ++kk) {
        float4 a0 = *(const float4*)(Hrow + kk * 32 + quad * 8);
        float4 a1 = *(const float4*)(Hrow + kk * 32 + quad * 8 + 4);
        bf16x8 bfr;
        bfr[0] = (short)f2bf(a0.x); bfr[1] = (short)f2bf(a0.y);
        bfr[2] = (short)f2bf(a0.z); bfr[3] = (short)f2bf(a0.w);
        bfr[4] = (short)f2bf(a1.x); bfr[5] = (short)f2bf(a1.y);
        bfr[6] = (short)f2bf(a1.z); bfr[7] = (short)f2bf(a1.w);
#pragma unroll
        for (int nt = 0; nt < 8; ++nt) {
            bf16x8 afr = *(const bf16x8*)(WT + (size_t)(nt * 16 + (lane & 15)) * DD +
                                          kk * 32 + quad * 8);
            acc[nt] = __builtin_amdgcn_mfma_f32_16x16x32_bf16(afr, bfr, acc[nt], 0, 0, 0);
        }
    }
    int c = cnt4[m] + cnt4[NN + m] + cnt4[2 * NN + m] + cnt4[3 * NN + m];
    float di = rsqrtf((float)(c + 1));
#pragma unroll
    for (int nt = 0; nt < 8; ++nt) {
        int n = nt * 16 + quad * 4;
        uint2 o;
        o.x = (uint)f2bf(acc[nt][0] * di) | ((uint)f2bf(acc[nt][1] * di) << 16);
        o.y = (uint)f2bf(acc[nt][2] * di) | ((uint)f2bf(acc[nt][3] * di) << 16);
        *(uint2*)(T + ((size_t)(n >> 5) * NN * 32) + (size_t)m * 32 + (n & 31)) = o;
    }
}

// ---------------- k_mm (layers 2,3): T = bf16( dinv * (A @ W) ), A bf16 row-major -------
__global__ __launch_bounds__(256) void k_mm(
    const ushort* __restrict__ H, const ushort* __restrict__ WT,
    const int* __restrict__ cnt4, ushort* __restrict__ T) {
    const int wave = threadIdx.x >> 6;
    const int lane = threadIdx.x & 63;
    const int m0w = blockIdx.x * 64 + wave * 16;
    if (m0w >= NN) return;
    const int m = m0w + (lane & 15);
    const int quad = lane >> 4;
    f32x4 acc[8];
#pragma unroll
    for (int nt = 0; nt < 8; ++nt) acc[nt] = (f32x4){0.f, 0.f, 0.f, 0.f};
    const ushort* Hrow = H + (size_t)m * DD;
#pragma unroll
    for (int kk = 0; kk < 4; ++kk) {
        bf16x8 bfr = *(const bf16x8*)(Hrow + kk * 32 + quad * 8);
#pragma unroll
        for (int nt = 0; nt < 8; ++nt) {
            bf16x8 afr = *(const bf16x8*)(WT + (size_t)(nt * 16 + (lane & 15)) * DD +
                                          kk * 32 + quad * 8);
            acc[nt] = __builtin_amdgcn_mfma_f32_16x16x32_bf16(afr, bfr, acc[nt], 0, 0, 0);
        }
    }
    int c = cnt4[m] + cnt4[NN + m] + cnt4[2 * NN + m] + cnt4[3 * NN + m];
    float di = rsqrtf((float)(c + 1));
#pragma unroll
    for (int nt = 0; nt < 8; ++nt) {
        int n = nt * 16 + quad * 4;
        uint2 o;
        o.x = (uint)f2bf(acc[nt][0] * di) | ((uint)f2bf(acc[nt][1] * di) << 16);
        o.y = (uint)f2bf(acc[nt][2] * di) | ((uint)f2bf(acc[nt][3] * di) << 16);
        *(uint2*)(T + ((size_t)(n >> 5) * NN * 32) + (size_t)m * 32 + (n & 31)) = o;
    }
}

// ---------------- k_agg: feature-chunked gather-sum ----------------
// Grid 25000: pass = blockIdx/6250 (feature chunk), 8 nodes/block, half-wave per node,
// 1 feature per lane (ushort loads, 64B rows resident in XCD L2).
__global__ __launch_bounds__(256) void k_agg(
    const ushort* __restrict__ Tc, const int* __restrict__ cnt4,
    const ushort* __restrict__ colb, const float* __restrict__ bias,
    ushort* __restrict__ A) {
    int b = blockIdx.x;
    int pass = b / AGG_NB;
    int node = (b % AGG_NB) * 8 + (threadIdx.x >> 5);   // NN == AGG_NB*8 exactly
    int f = threadIdx.x & 31;
    const ushort* Tp = Tc + (size_t)pass * NN * 32;
    float ax = bf2f((uint)Tp[(size_t)node * 32 + f]);   // self-loop (pre-scaled)
    int c0 = cnt4[node], c1 = cnt4[NN + node];
    int c2 = cnt4[2 * NN + node], c3 = cnt4[3 * NN + node];
    const ushort* row = colb + ((size_t)node << 7);
#pragma unroll
    for (int s = 0; s < 4; ++s) {
        int cs = (s == 0) ? c0 : (s == 1) ? c1 : (s == 2) ? c2 : c3;
        if (cs > SUBCAP) cs = SUBCAP;
        const ushort* bl = row + s * SUBCAP;
        int e = 0;
        for (; e + 3 < cs; e += 4) {
            int j0 = bl[e], j1 = bl[e + 1], j2 = bl[e + 2], j3 = bl[e + 3];
            float v0 = bf2f((uint)Tp[(size_t)j0 * 32 + f]);
            float v1 = bf2f((uint)Tp[(size_t)j1 * 32 + f]);
            float v2 = bf2f((uint)Tp[(size_t)j2 * 32 + f]);
            float v3 = bf2f((uint)Tp[(size_t)j3 * 32 + f]);
            ax += (v0 + v1) + (v2 + v3);
        }
        for (; e < cs; ++e) ax += bf2f((uint)Tp[(size_t)bl[e] * 32 + f]);
    }
    float di = rsqrtf((float)(c0 + c1 + c2 + c3 + 1));
    float o = fmaxf(fmaf(ax, di, bias[pass * 32 + f]), 0.f);
    A[(size_t)node * DD + pass * 32 + f] = f2bf(o);
}

// ---------------- k_mm_final: out = A @ Wfc + bfc (fp32 out) ----------------
__global__ __launch_bounds__(256) void k_mm_final(
    const ushort* __restrict__ H, const ushort* __restrict__ WT,
    const float* __restrict__ bb, float* __restrict__ out) {
    const int wave = threadIdx.x >> 6;
    const int lane = threadIdx.x & 63;
    const int m0w = blockIdx.x * 64 + wave * 16;
    if (m0w >= NN) return;
    const int m = m0w + (lane & 15);
    const int quad = lane >> 4;
    f32x4 acc[4];
#pragma unroll
    for (int nt = 0; nt < 4; ++nt) acc[nt] = (f32x4){0.f, 0.f, 0.f, 0.f};
    const ushort* Hrow = H + (size_t)m * DD;
#pragma unroll
    for (int kk = 0; kk < 4; ++kk) {
        bf16x8 bfr = *(const bf16x8*)(Hrow + kk * 32 + quad * 8);
#pragma unroll
        for (int nt = 0; nt < 4; ++nt) {
            bf16x8 afr = *(const bf16x8*)(WT + (size_t)(nt * 16 + (lane & 15)) * DD +
                                          kk * 32 + quad * 8);
            acc[nt] = __builtin_amdgcn_mfma_f32_16x16x32_bf16(afr, bfr, acc[nt], 0, 0, 0);
        }
    }
#pragma unroll
    for (int nt = 0; nt < 4; ++nt) {
        int n = nt * 16 + quad * 4;
        float4 bvals = *(const float4*)(bb + n);
        float4 o = {acc[nt][0] + bvals.x, acc[nt][1] + bvals.y,
                    acc[nt][2] + bvals.z, acc[nt][3] + bvals.w};
        *(float4*)(out + (size_t)m * DOUTC + n) = o;
    }
}

// ---------------- launch ----------------
extern "C" void kernel_launch(void* const* d_in, const int* in_sizes, int n_in,
                              void* d_out, int out_size, void* d_ws, size_t ws_size,
                              hipStream_t stream) {
    const float* x   = (const float*)d_in[0];
    const int*   ei  = (const int*)d_in[1];
    const float* W1  = (const float*)d_in[2];
    const float* b1  = (const float*)d_in[3];
    const float* W2  = (const float*)d_in[4];
    const float* b2  = (const float*)d_in[5];
    const float* W3  = (const float*)d_in[6];
    const float* b3  = (const float*)d_in[7];
    const float* Wfc = (const float*)d_in[8];
    const float* bfc = (const float*)d_in[9];

    char* ws = (char*)d_ws;
    size_t off = 0;
    auto take = [&](size_t bytes) {
        void* p = ws + off;
        off = (off + bytes + 255) & ~(size_t)255;
        return p;
    };
    int*    cnt4 = (int*)take(CNT4_BYTES);                 // 800 KB, [sub][node]
    ushort* colb = (ushort*)take((size_t)NN * 256);        // 12.8 MB (4 subs x 32 slots)
    ushort* T    = (ushort*)take((size_t)NN * DD * 2);     // 12.8 MB, 4 feature chunks
    ushort* A    = (ushort*)take((size_t)NN * DD * 2);     // 12.8 MB row-major
    ushort* WT1  = (ushort*)take((size_t)DD * DD * 2);
    ushort* WT2  = (ushort*)take((size_t)DD * DD * 2);
    ushort* WT3  = (ushort*)take((size_t)DD * DD * 2);
    ushort* WTfc = (ushort*)take((size_t)DOUTC * DD * 2);

    const int* src = ei;
    const int* dst = ei + EE;

    PreArgs pa;
    pa.w1 = W1; pa.w2 = W2; pa.w3 = W3; pa.wfc = Wfc;
    pa.wt1 = WT1; pa.wt2 = WT2; pa.wt3 = WT3; pa.wtfc = WTfc;
    pa.cnt4 = (char*)cnt4;
    k_pre<<<CNT4_ZBLKS + 192 + 32, 256, 0, stream>>>(pa);

    const int mm_grid  = (NN + 63) / 64;   // 782
    const int agg_grid = 4 * AGG_NB;       // 25000

    k_bucket<<<BUCKET_BLKS, 256, 0, stream>>>(src, dst, cnt4, colb);
    k_mm1<<<mm_grid, 256, 0, stream>>>(x, WT1, cnt4, T);
    k_agg<<<agg_grid, 256, 0, stream>>>(T, cnt4, colb, b1, A);
    k_mm<<<mm_grid, 256, 0, stream>>>(A, WT2, cnt4, T);
    k_agg<<<agg_grid, 256, 0, stream>>>(T, cnt4, colb, b2, A);
    k_mm<<<mm_grid, 256, 0, stream>>>(A, WT3, cnt4, T);
    k_agg<<<agg_grid, 256, 0, stream>>>(T, cnt4, colb, b3, A);
    k_mm_final<<<mm_grid, 256, 0, stream>>>(A, WTfc, bfc, (float*)d_out);
}

// Round 9
// 376.874 us; speedup vs baseline: 1.4464x; 1.4464x over previous
//
#include <hip/hip_runtime.h>

#define NN 50000
#define EE 800000
#define DD 128
#define DOUTC 64
#define SLOTS 62          // per-node slots; degree ~Poisson(16), P(>62) ~ 1e-16
#define ROWB 128          // bucket row bytes: 4B cnt header + 62*2B slots
#define BUCKET_BLKS 3125  // EE / 256
#define ZERO_BLKS 1563    // ceil(NN*ROWB / (256*16))

typedef unsigned int uint;
typedef unsigned short ushort;
typedef __attribute__((ext_vector_type(8))) short bf16x8;
typedef __attribute__((ext_vector_type(4))) float f32x4;

__device__ __forceinline__ float bf2f(uint b) { return __uint_as_float(b << 16); }
__device__ __forceinline__ ushort f2bf(float f) {
    uint u = __float_as_uint(f);
    u += 0x7fffu + ((u >> 16) & 1u);   // round-to-nearest-even
    return (ushort)(u >> 16);
}

// ---------------- k_pre: zero bucket rows + transpose-convert weights to bf16 [n][k] ----
struct PreArgs {
    const float *w1, *w2, *w3, *wfc;
    ushort *wt1, *wt2, *wt3, *wtfc;
    char* colb;
};

__global__ __launch_bounds__(256) void k_pre(PreArgs a) {
    int b = blockIdx.x, t = threadIdx.x;
    if (b < ZERO_BLKS) {
        size_t i = ((size_t)b * 256 + t) * 16;
        if (i < (size_t)NN * ROWB) *(uint4*)(a.colb + i) = (uint4){0, 0, 0, 0};
    } else if (b < ZERO_BLKS + 192) {
        int b2 = b - ZERO_BLKS;
        const float* w = (b2 < 64) ? a.w1 : (b2 < 128) ? a.w2 : a.w3;
        ushort* wt = (b2 < 64) ? a.wt1 : (b2 < 128) ? a.wt2 : a.wt3;
        int idx = (b2 & 63) * 256 + t;         // idx = k*128 + n
        int k = idx >> 7, n = idx & 127;
        wt[n * DD + k] = f2bf(w[idx]);
    } else {
        int idx = (b - ZERO_BLKS - 192) * 256 + t;  // idx = k*64 + n
        int k = idx >> 6, n = idx & 63;
        a.wtfc[n * DD + k] = f2bf(a.wfc[idx]);
    }
}

// ---------------- k_bucket: edge scatter; cnt header and slots share the 128B row -------
__global__ __launch_bounds__(256) void k_bucket(
    const int* __restrict__ src, const int* __restrict__ dst,
    char* __restrict__ colb) {
    int e = blockIdx.x * 256 + threadIdx.x;    // EE == BUCKET_BLKS*256 exactly
    int d = dst[e];
    int s = src[e];
    char* row = colb + ((size_t)d << 7);
    int p = atomicAdd((int*)row, 1);
    if (p < SLOTS) *(ushort*)(row + 4 + 2 * p) = (ushort)s;
}

// ---------------- k_mm1: T[m,:] = bf16( dinv[m] * (x[m,:] @ W1) ), x fp32 ----------------
// D lane layout (16x16x32): col = lane&15 = m, row = quad*4 + reg = n.
__global__ __launch_bounds__(256) void k_mm1(
    const float* __restrict__ X, const ushort* __restrict__ WT,
    const char* __restrict__ colb, ushort* __restrict__ T) {
    const int wave = threadIdx.x >> 6;
    const int lane = threadIdx.x & 63;
    const int m0w = blockIdx.x * 64 + wave * 16;
    if (m0w >= NN) return;                     // NN % 16 == 0
    const int m = m0w + (lane & 15);
    const int quad = lane >> 4;
    f32x4 acc[8];
#pragma unroll
    for (int nt = 0; nt < 8; ++nt) acc[nt] = (f32x4){0.f, 0.f, 0.f, 0.f};
    const float* Hrow = X + (size_t)m * DD;
#pragma unroll
    for (int kk = 0; kk < 4; ++kk) {
        float4 a0 = *(const float4*)(Hrow + kk * 32 + quad * 8);
        float4 a1 = *(const float4*)(Hrow + kk * 32 + quad * 8 + 4);
        bf16x8 bfr;
        bfr[0] = (short)f2bf(a0.x); bfr[1] = (short)f2bf(a0.y);
        bfr[2] = (short)f2bf(a0.z); bfr[3] = (short)f2bf(a0.w);
        bfr[4] = (short)f2bf(a1.x); bfr[5] = (short)f2bf(a1.y);
        bfr[6] = (short)f2bf(a1.z); bfr[7] = (short)f2bf(a1.w);
#pragma unroll
        for (int nt = 0; nt < 8; ++nt) {
            bf16x8 afr = *(const bf16x8*)(WT + (size_t)(nt * 16 + (lane & 15)) * DD +
                                          kk * 32 + quad * 8);
            acc[nt] = __builtin_amdgcn_mfma_f32_16x16x32_bf16(afr, bfr, acc[nt], 0, 0, 0);
        }
    }
    int c = *(const int*)(colb + ((size_t)m << 7));
    float di = rsqrtf((float)(c + 1));
#pragma unroll
    for (int nt = 0; nt < 8; ++nt) {
        int n = nt * 16 + quad * 4;
        uint2 o;
        o.x = (uint)f2bf(acc[nt][0] * di) | ((uint)f2bf(acc[nt][1] * di) << 16);
        o.y = (uint)f2bf(acc[nt][2] * di) | ((uint)f2bf(acc[nt][3] * di) << 16);
        *(uint2*)(T + (size_t)m * DD + n) = o;
    }
}

// ---------------- k_aggmm: fused aggregation + next-layer GEMM ----------------
// Phase 1 (per wave, no barrier): for 16 nodes, gather pre-scaled T rows of neighbors,
//   A-row = relu(di*(sum)+bias) packed bf16 into wave-private LDS slice (+ di stash).
// Phase 2: MFMA T2[m,:] = di2 * (A[m,:] @ W) from LDS B-fragments (wave-local rows).
// FINAL variant: out = A @ Wfc + bfc, fp32, 64 cols, no scaling.
template <bool FINAL>
__global__ __launch_bounds__(256) void k_aggmm(
    const ushort* __restrict__ T, const char* __restrict__ colb,
    const float* __restrict__ bias, const ushort* __restrict__ WT,
    const float* __restrict__ bfc, void* __restrict__ out_) {
    __shared__ ushort As[4][16][136];   // 272B row stride (16B-aligned), ~17.4 KB
    __shared__ float sdi[4][16];
    const int wave = threadIdx.x >> 6;
    const int lane = threadIdx.x & 63;
    const uint* Tv = (const uint*)T;

    // ---- phase 1: aggregate 16 nodes (wave-local) ----
    for (int t = 0; t < 16; ++t) {
        int node = blockIdx.x * 64 + wave * 16 + t;
        float ax = 0.f, ay = 0.f, di = 1.f;
        if (node < NN) {
            const char* row = colb + ((size_t)node << 7);
            int c = *(const int*)row;
            int end = c < SLOTS ? c : SLOTS;
            const ushort* bl = (const ushort*)(row + 4);
            uint w0 = Tv[(size_t)node * 64 + lane];      // self-loop (pre-scaled)
            ax = bf2f(w0 & 0xffffu); ay = bf2f(w0 >> 16);
            int e = 0;
            for (; e + 7 < end; e += 8) {
                uint vv[8];
#pragma unroll
                for (int q = 0; q < 8; ++q) vv[q] = Tv[(size_t)bl[e + q] * 64 + lane];
#pragma unroll
                for (int q = 0; q < 8; ++q) {
                    ax += bf2f(vv[q] & 0xffffu);
                    ay += bf2f(vv[q] >> 16);
                }
            }
            for (; e < end; ++e) {
                uint v = Tv[(size_t)bl[e] * 64 + lane];
                ax += bf2f(v & 0xffffu);
                ay += bf2f(v >> 16);
            }
            di = rsqrtf((float)(c + 1));
            float2 bv = ((const float2*)bias)[lane];
            ax = fmaxf(fmaf(ax, di, bv.x), 0.f);
            ay = fmaxf(fmaf(ay, di, bv.y), 0.f);
        }
        *(uint*)&As[wave][t][2 * lane] = (uint)f2bf(ax) | ((uint)f2bf(ay) << 16);
        if (lane == 0) sdi[wave][t] = di;
    }
    // wave-private LDS slice: no __syncthreads needed (compiler waits lgkmcnt)

    // ---- phase 2: MFMA over the wave's 16 rows ----
    const int mloc = lane & 15;
    const int quad = lane >> 4;
    const int m = blockIdx.x * 64 + wave * 16 + mloc;
    const int NT = FINAL ? 4 : 8;
    f32x4 acc[8];
#pragma unroll
    for (int nt = 0; nt < 8; ++nt) acc[nt] = (f32x4){0.f, 0.f, 0.f, 0.f};
#pragma unroll
    for (int kk = 0; kk < 4; ++kk) {
        bf16x8 bfr = *(const bf16x8*)&As[wave][mloc][kk * 32 + quad * 8];
#pragma unroll
        for (int nt = 0; nt < NT; ++nt) {
            bf16x8 afr = *(const bf16x8*)(WT + (size_t)(nt * 16 + mloc) * DD +
                                          kk * 32 + quad * 8);
            acc[nt] = __builtin_amdgcn_mfma_f32_16x16x32_bf16(afr, bfr, acc[nt], 0, 0, 0);
        }
    }
    if (m >= NN) return;
    if (FINAL) {
        float* out = (float*)out_;
#pragma unroll
        for (int nt = 0; nt < 4; ++nt) {
            int n = nt * 16 + quad * 4;
            float4 bvals = *(const float4*)(bfc + n);
            float4 o = {acc[nt][0] + bvals.x, acc[nt][1] + bvals.y,
                        acc[nt][2] + bvals.z, acc[nt][3] + bvals.w};
            *(float4*)(out + (size_t)m * DOUTC + n) = o;
        }
    } else {
        ushort* T2 = (ushort*)out_;
        float di2 = sdi[wave][mloc];
#pragma unroll
        for (int nt = 0; nt < 8; ++nt) {
            int n = nt * 16 + quad * 4;
            uint2 o;
            o.x = (uint)f2bf(acc[nt][0] * di2) | ((uint)f2bf(acc[nt][1] * di2) << 16);
            o.y = (uint)f2bf(acc[nt][2] * di2) | ((uint)f2bf(acc[nt][3] * di2) << 16);
            *(uint2*)(T2 + (size_t)m * DD + n) = o;
        }
    }
}

// ---------------- launch ----------------
extern "C" void kernel_launch(void* const* d_in, const int* in_sizes, int n_in,
                              void* d_out, int out_size, void* d_ws, size_t ws_size,
                              hipStream_t stream) {
    const float* x   = (const float*)d_in[0];
    const int*   ei  = (const int*)d_in[1];
    const float* W1  = (const float*)d_in[2];
    const float* b1  = (const float*)d_in[3];
    const float* W2  = (const float*)d_in[4];
    const float* b2  = (const float*)d_in[5];
    const float* W3  = (const float*)d_in[6];
    const float* b3  = (const float*)d_in[7];
    const float* Wfc = (const float*)d_in[8];
    const float* bfc = (const float*)d_in[9];

    char* ws = (char*)d_ws;
    size_t off = 0;
    auto take = [&](size_t bytes) {
        void* p = ws + off;
        off = (off + bytes + 255) & ~(size_t)255;
        return p;
    };
    char*   colb = (char*)take((size_t)NN * ROWB);         // 6.4 MB (cnt hdr + slots)
    ushort* T    = (ushort*)take((size_t)NN * DD * 2);     // 12.8 MB
    ushort* T2   = (ushort*)take((size_t)NN * DD * 2);     // 12.8 MB
    ushort* WT1  = (ushort*)take((size_t)DD * DD * 2);
    ushort* WT2  = (ushort*)take((size_t)DD * DD * 2);
    ushort* WT3  = (ushort*)take((size_t)DD * DD * 2);
    ushort* WTfc = (ushort*)take((size_t)DOUTC * DD * 2);

    const int* src = ei;
    const int* dst = ei + EE;

    PreArgs pa;
    pa.w1 = W1; pa.w2 = W2; pa.w3 = W3; pa.wfc = Wfc;
    pa.wt1 = WT1; pa.wt2 = WT2; pa.wt3 = WT3; pa.wtfc = WTfc;
    pa.colb = colb;
    k_pre<<<ZERO_BLKS + 192 + 32, 256, 0, stream>>>(pa);

    const int mm_grid = (NN + 63) / 64;   // 782

    k_bucket<<<BUCKET_BLKS, 256, 0, stream>>>(src, dst, colb);
    k_mm1<<<mm_grid, 256, 0, stream>>>(x, WT1, colb, T);
    // agg(layer1,b1) fused with GEMM(W2) -> T2
    k_aggmm<false><<<mm_grid, 256, 0, stream>>>(T, colb, b1, WT2, nullptr, T2);
    // agg(layer2,b2) fused with GEMM(W3) -> T
    k_aggmm<false><<<mm_grid, 256, 0, stream>>>(T2, colb, b2, WT3, nullptr, T);
    // agg(layer3,b3) fused with final GEMM(Wfc)+bfc -> out (fp32)
    k_aggmm<true><<<mm_grid, 256, 0, stream>>>(T, colb, b3, WTfc, bfc, d_out);
}